// Round 8
// baseline (1051.637 us; speedup 1.0000x reference)
//
#include <hip/hip_runtime.h>
#include <hip/hip_bf16.h>

#define D_HID 32
#define D_IN 128
#define NEG 0.2f
#define BSH 7          // log2 bucket size
#define BSZ 128        // dst nodes per bucket
#define MAXB 1024      // max buckets (N <= 131072)

typedef unsigned short u16;

__device__ __forceinline__ float b2f(u16 u){
  union { unsigned int i; float f; } c; c.i = ((unsigned int)u) << 16; return c.f;
}

// dtype-agnostic float load: f32 ? fp32[i] : bf16[i]
__device__ __forceinline__ float ldf(const void* __restrict__ p, int f32, long long i){
  return f32 ? ((const float*)p)[i] : b2f(((const u16*)p)[i]);
}

__device__ __forceinline__ int atomAddI(int* p, int v){
  return __hip_atomic_fetch_add(p, v, __ATOMIC_RELAXED, __HIP_MEMORY_SCOPE_AGENT);
}

// flags[0]: edge_index is int64-layout (high dwords of first 64 entries all zero).
// flags[1]: float inputs are fp32 (u16-word exponent sanity over 256 words).
__global__ void detect_flags(const int* __restrict__ ei, const u16* __restrict__ xw,
                             int* __restrict__ flags){
  __shared__ int insane_s, nz_s;
  int t = threadIdx.x;                      // 256 threads
  if (t == 0){ insane_s = 0; nz_s = 0; }
  __syncthreads();
  int pred = (t < 64) ? (ei[2*t+1] != 0) : 0;
  int e = (xw[t] >> 7) & 0xFF;
  int bad = (e < 100 || e > 140) ? 1 : 0;
  #pragma unroll
  for (int off = 32; off >= 1; off >>= 1){
    bad  += __shfl_down(bad,  off, 64);
    pred += __shfl_down(pred, off, 64);
  }
  if ((t & 63) == 0){
    atomicAdd(&insane_s, bad);
    atomicAdd(&nz_s, pred);
  }
  __syncthreads();
  if (t == 0){
    flags[0] = (nz_s == 0) ? 1 : 0;
    flags[1] = (insane_s > 16) ? 1 : 0;
  }
}

__device__ __forceinline__ void edge_nodes(const int* __restrict__ ei, int E_, int is64,
                                           int e, int& src, int& dst){
  if (is64){ src = ei[2*e]; dst = ei[2*E_ + 2*e]; }
  else     { src = ei[e];   dst = ei[E_ + e]; }
}

// ---------------- node transform (fp32-exact, verified r7) ----------------
template<int K>
__global__ void node_gemm(const void* __restrict__ X,
                          const void* __restrict__ Wl,
                          const void* __restrict__ Wr,
                          const int* __restrict__ flags, int force_f32,
                          float* __restrict__ xl, float* __restrict__ xr, int N_)
{
  int n = blockIdx.x * blockDim.x + threadIdx.x;
  if (n >= N_) return;
  int f32 = force_f32 | flags[1];
  float accl[32], accr[32];
  #pragma unroll
  for (int c = 0; c < 32; ++c){ accl[c] = 0.f; accr[c] = 0.f; }

  if (f32){
    const float* xrow = (const float*)X + (size_t)n * K;
    const float* wl = (const float*)Wl;
    const float* wr = (const float*)Wr;
    for (int k0 = 0; k0 < K; k0 += 4){
      float4 xv = *(const float4*)(xrow + k0);
      #pragma unroll
      for (int kk = 0; kk < 4; ++kk){
        float xs = kk==0 ? xv.x : kk==1 ? xv.y : kk==2 ? xv.z : xv.w;
        int k = k0 + kk;
        #pragma unroll
        for (int c = 0; c < 32; c += 4){
          float4 wl4 = *(const float4*)(wl + k*D_HID + c);
          float4 wr4 = *(const float4*)(wr + k*D_HID + c);
          accl[c+0] = fmaf(xs, wl4.x, accl[c+0]);
          accl[c+1] = fmaf(xs, wl4.y, accl[c+1]);
          accl[c+2] = fmaf(xs, wl4.z, accl[c+2]);
          accl[c+3] = fmaf(xs, wl4.w, accl[c+3]);
          accr[c+0] = fmaf(xs, wr4.x, accr[c+0]);
          accr[c+1] = fmaf(xs, wr4.y, accr[c+1]);
          accr[c+2] = fmaf(xs, wr4.z, accr[c+2]);
          accr[c+3] = fmaf(xs, wr4.w, accr[c+3]);
        }
      }
    }
  } else {
    for (int k = 0; k < K; ++k){
      float xs = ldf(X, 0, (long long)n*K + k);
      #pragma unroll
      for (int c = 0; c < 32; ++c){
        accl[c] = fmaf(xs, ldf(Wl, 0, k*D_HID + c), accl[c]);
        accr[c] = fmaf(xs, ldf(Wr, 0, k*D_HID + c), accr[c]);
      }
    }
  }

  float* lo = xl + (size_t)n * D_HID;
  float* ro = xr + (size_t)n * D_HID;
  #pragma unroll
  for (int c = 0; c < 32; c += 4){
    *(float4*)(lo + c) = make_float4(accl[c], accl[c+1], accl[c+2], accl[c+3]);
    *(float4*)(ro + c) = make_float4(accr[c], accr[c+1], accr[c+2], accr[c+3]);
  }
}

// ---------------- bucket count (LDS histogram, then one flush per block) ---------
__global__ void bucket_count(const int* __restrict__ ei, const int* __restrict__ flags,
                             int* __restrict__ gcnt, int E_, int B_){
  __shared__ int hist[MAXB];
  for (int i = threadIdx.x; i < B_; i += 256) hist[i] = 0;
  __syncthreads();
  int chunk = (E_ + gridDim.x - 1) / gridDim.x;
  int s = blockIdx.x * chunk;
  int e = s + chunk; if (e > E_) e = E_;
  int is64 = flags[0];
  for (int i = s + (int)threadIdx.x; i < e; i += 256){
    int dst = is64 ? ei[2*E_ + 2*i] : ei[E_ + i];
    atomicAdd(&hist[dst >> BSH], 1);
  }
  __syncthreads();
  for (int i = threadIdx.x; i < B_; i += 256)
    if (hist[i]) (void)atomAddI(&gcnt[i], hist[i]);
}

// ---------------- exclusive scan over bucket counts (single block) ----------------
__global__ void scan_buckets(const int* __restrict__ gcnt, int* __restrict__ offsets,
                             int* __restrict__ cursor, int B_){
  __shared__ int sd[1024];
  int t = threadIdx.x;
  int v = (t < B_) ? gcnt[t] : 0;
  sd[t] = v;
  __syncthreads();
  for (int off = 1; off < 1024; off <<= 1){
    int tmp = (t >= off) ? sd[t-off] : 0;
    __syncthreads();
    sd[t] += tmp;
    __syncthreads();
  }
  if (t < B_){
    int excl = sd[t] - v;
    offsets[t] = excl;
    cursor[t]  = excl;
    if (t == B_-1) offsets[B_] = sd[t];
  }
}

// ---------------- bucket scatter with per-block range reservation ----------------
// Packs (src << 7) | dstLocal into 4B. Each block reserves contiguous per-bucket
// ranges (ONE global atomic per block-bucket), so global writes are dense runs.
__global__ void bucket_scatter(const int* __restrict__ ei, const int* __restrict__ flags,
                               int* __restrict__ cursor, unsigned* __restrict__ seg,
                               int E_, int B_){
  __shared__ int hist[MAXB];
  __shared__ int bbase[MAXB];
  for (int i = threadIdx.x; i < B_; i += 256) hist[i] = 0;
  __syncthreads();
  int chunk = (E_ + gridDim.x - 1) / gridDim.x;
  int s = blockIdx.x * chunk;
  int e = s + chunk; if (e > E_) e = E_;
  int is64 = flags[0];
  for (int i = s + (int)threadIdx.x; i < e; i += 256){
    int dst = is64 ? ei[2*E_ + 2*i] : ei[E_ + i];
    atomicAdd(&hist[dst >> BSH], 1);
  }
  __syncthreads();
  for (int i = threadIdx.x; i < B_; i += 256){
    int c = hist[i];
    bbase[i] = c ? atomAddI(&cursor[i], c) : 0;
  }
  __syncthreads();
  for (int i = threadIdx.x; i < B_; i += 256) hist[i] = 0;  // reuse as local offset
  __syncthreads();
  for (int i = s + (int)threadIdx.x; i < e; i += 256){
    int src, dst;
    edge_nodes(ei, E_, is64, i, src, dst);
    int b = dst >> BSH;
    int pos = bbase[b] + atomicAdd(&hist[b], 1);
    seg[pos] = ((unsigned)src << BSH) | (unsigned)(dst & (BSZ-1));
  }
}

// ---------------- bucketed gather: softmax + weighted sum + bias -----------------
// One block per 128-dst bucket. acc/ssum/xr-slice in LDS; streams the bucket's
// edge segment; half-wave per edge (lane k of 32 owns feature k), 4 edges
// unrolled for load ILP. Inner reduce is the verified r7 pattern; all guard
// predicates are half-wave-uniform.
__global__ __launch_bounds__(256) void gat_bucket(
    const unsigned* __restrict__ seg, const int* __restrict__ offsets,
    const float* __restrict__ xl, const float* __restrict__ xr,
    const void* __restrict__ att, const void* __restrict__ bias,
    const int* __restrict__ flags,
    float* __restrict__ outp, int N_, int do_relu)
{
  __shared__ float acc[BSZ][32];    // 16 KB; bank = k -> conflict-free per half-wave
  __shared__ float xrs[BSZ][32];    // 16 KB
  __shared__ float ssum[BSZ];
  int b = blockIdx.x;
  int t = threadIdx.x;
  int base = offsets[b], cnt = offsets[b+1] - base;
  int nd = N_ - b*BSZ; if (nd > BSZ) nd = BSZ;   // dsts in this bucket

  for (int i = t; i < BSZ*32; i += 256) ((float*)acc)[i] = 0.f;
  for (int i = t; i < BSZ; i += 256) ssum[i] = 0.f;
  for (int i = t; i < nd*32; i += 256) ((float*)xrs)[i] = xr[(size_t)b*BSZ*32 + i];
  __syncthreads();

  int f32 = flags[1];
  int lane = t & 63;
  int k = lane & 31;
  int slot = t >> 5;                 // 0..7 half-wave slot
  float attk = ldf(att, f32, k);

  for (int i0 = slot; i0 < cnt; i0 += 32){     // 4 edges per iter: i0 + {0,8,16,24}
    unsigned en[4]; float xlv[4]; int valid[4];
    #pragma unroll
    for (int u = 0; u < 4; ++u){
      int i = i0 + u*8;
      valid[u] = (i < cnt);
      en[u] = valid[u] ? seg[base + i] : 0u;
      xlv[u] = valid[u] ? xl[(size_t)(en[u] >> BSH)*D_HID + k] : 0.f;
    }
    #pragma unroll
    for (int u = 0; u < 4; ++u){
      if (valid[u]){                 // uniform within the half-wave
        int dl = en[u] & (BSZ-1);
        float h = xlv[u] + xrs[dl][k];
        h = h > 0.f ? h : NEG*h;
        float p = h * attk;
        p += __shfl_xor(p, 16, 32);
        p += __shfl_xor(p,  8, 32);
        p += __shfl_xor(p,  4, 32);
        p += __shfl_xor(p,  2, 32);
        p += __shfl_xor(p,  1, 32);
        p = fminf(p, 60.f);          // safety clamp; real logits |.| <~ 15
        float ev = __expf(p);
        atomicAdd(&acc[dl][k], ev * xlv[u]);
        if (k == 0) atomicAdd(&ssum[dl], ev);
      }
    }
  }
  __syncthreads();

  // epilogue: 256 threads write 32 rows/iter as float4 (coalesced)
  for (int r0 = 0; r0 < BSZ; r0 += 32){
    int r = r0 + (t >> 3);
    int c = (t & 7) * 4;
    if (r < nd){
      float s = ssum[r] + 1e-16f;
      float4 o;
      o.x = acc[r][c+0]/s + ldf(bias, f32, c+0);
      o.y = acc[r][c+1]/s + ldf(bias, f32, c+1);
      o.z = acc[r][c+2]/s + ldf(bias, f32, c+2);
      o.w = acc[r][c+3]/s + ldf(bias, f32, c+3);
      if (do_relu){
        o.x = fmaxf(o.x, 0.f); o.y = fmaxf(o.y, 0.f);
        o.z = fmaxf(o.z, 0.f); o.w = fmaxf(o.w, 0.f);
      }
      *(float4*)(outp + (size_t)(b*BSZ + r)*D_HID + c) = o;
    }
  }
}

extern "C" void kernel_launch(void* const* d_in, const int* in_sizes, int n_in,
                              void* d_out, int out_size, void* d_ws, size_t ws_size,
                              hipStream_t stream)
{
  const void* x   = d_in[0];
  const int*  ei  = (const int*)d_in[1];
  const void* W1l = d_in[2];
  const void* W1r = d_in[3];
  const void* att1= d_in[4];
  const void* b1  = d_in[5];
  const void* W2l = d_in[6];
  const void* W2r = d_in[7];
  const void* att2= d_in[8];
  const void* b2  = d_in[9];
  float* out = (float*)d_out;

  int N_ = in_sizes[0] / D_IN;
  int E_ = in_sizes[1] / 2;
  int B_ = (N_ + BSZ - 1) / BSZ;    // 782 buckets for N=100000

  char* ws = (char*)d_ws;
  size_t off = 0;
  auto carve = [&](size_t bytes) -> char* {
    char* p = ws + off;
    off += (bytes + 255) & ~(size_t)255;
    return p;
  };
  float*    xl      = (float*)   carve((size_t)N_ * D_HID * 4);
  float*    xr      = (float*)   carve((size_t)N_ * D_HID * 4);
  float*    h       = (float*)   carve((size_t)N_ * D_HID * 4);
  unsigned* seg     = (unsigned*)carve((size_t)E_ * 4);
  int*      offsets = (int*)     carve((size_t)(MAXB + 1) * 4);
  int*      gcnt    = (int*)     carve((size_t)MAXB * 4);
  int*      cursor  = (int*)     carve((size_t)MAXB * 4);
  int*      flags   = (int*)     carve(256);

  const int tpb = 256;
  int gN  = (N_ + tpb - 1) / tpb;

  detect_flags<<<1, 256, 0, stream>>>(ei, (const u16*)x, flags);

  // ---- bucketed CSR build (shared by both layers) ----
  hipMemsetAsync(gcnt, 0, (size_t)MAXB * 4, stream);
  bucket_count<<<256, tpb, 0, stream>>>(ei, flags, gcnt, E_, B_);
  scan_buckets<<<1, 1024, 0, stream>>>(gcnt, offsets, cursor, B_);
  bucket_scatter<<<256, tpb, 0, stream>>>(ei, flags, cursor, seg, E_, B_);

  // ---- layer 1 ----
  node_gemm<D_IN><<<gN, tpb, 0, stream>>>(x, W1l, W1r, flags, 0, xl, xr, N_);
  gat_bucket<<<B_, tpb, 0, stream>>>(seg, offsets, xl, xr, att1, b1, flags, h, N_, 1);

  // ---- layer 2 ----
  node_gemm<D_HID><<<gN, tpb, 0, stream>>>(h, W2l, W2r, flags, 1, xl, xr, N_);
  gat_bucket<<<B_, tpb, 0, stream>>>(seg, offsets, xl, xr, att2, b2, flags, out, N_, 0);
}

// Round 9
// 385.801 us; speedup vs baseline: 2.7259x; 2.7259x over previous
//
#include <hip/hip_runtime.h>
#include <hip/hip_bf16.h>

#define D_HID 32
#define D_IN 128
#define NEG 0.2f
#define BSH 7          // log2 bucket size
#define BSZ 128        // dst nodes per bucket
#define MAXB 1024      // max buckets (N <= 131072)

typedef unsigned short u16;

__device__ __forceinline__ float b2f(u16 u){
  union { unsigned int i; float f; } c; c.i = ((unsigned int)u) << 16; return c.f;
}

__device__ __forceinline__ float ldf(const void* __restrict__ p, int f32, long long i){
  return f32 ? ((const float*)p)[i] : b2f(((const u16*)p)[i]);
}

__device__ __forceinline__ int atomAddI(int* p, int v){
  return __hip_atomic_fetch_add(p, v, __ATOMIC_RELAXED, __HIP_MEMORY_SCOPE_AGENT);
}

// flags[0]: edge_index is int64-layout. flags[1]: float inputs are fp32.
__global__ void detect_flags(const int* __restrict__ ei, const u16* __restrict__ xw,
                             int* __restrict__ flags){
  __shared__ int insane_s, nz_s;
  int t = threadIdx.x;
  if (t == 0){ insane_s = 0; nz_s = 0; }
  __syncthreads();
  int pred = (t < 64) ? (ei[2*t+1] != 0) : 0;
  int e = (xw[t] >> 7) & 0xFF;
  int bad = (e < 100 || e > 140) ? 1 : 0;
  #pragma unroll
  for (int off = 32; off >= 1; off >>= 1){
    bad  += __shfl_down(bad,  off, 64);
    pred += __shfl_down(pred, off, 64);
  }
  if ((t & 63) == 0){
    atomicAdd(&insane_s, bad);
    atomicAdd(&nz_s, pred);
  }
  __syncthreads();
  if (t == 0){
    flags[0] = (nz_s == 0) ? 1 : 0;
    flags[1] = (insane_s > 16) ? 1 : 0;
  }
}

__device__ __forceinline__ void edge_nodes(const int* __restrict__ ei, int E_, int is64,
                                           int e, int& src, int& dst){
  if (is64){ src = ei[2*e]; dst = ei[2*E_ + 2*e]; }
  else     { src = ei[e];   dst = ei[E_ + e]; }
}

// ---------------- node transform (fp32-exact, verified r7) ----------------
template<int K>
__global__ void node_gemm(const void* __restrict__ X,
                          const void* __restrict__ Wl,
                          const void* __restrict__ Wr,
                          const int* __restrict__ flags, int force_f32,
                          float* __restrict__ xl, float* __restrict__ xr, int N_)
{
  int n = blockIdx.x * blockDim.x + threadIdx.x;
  if (n >= N_) return;
  int f32 = force_f32 | flags[1];
  float accl[32], accr[32];
  #pragma unroll
  for (int c = 0; c < 32; ++c){ accl[c] = 0.f; accr[c] = 0.f; }

  if (f32){
    const float* xrow = (const float*)X + (size_t)n * K;
    const float* wl = (const float*)Wl;
    const float* wr = (const float*)Wr;
    for (int k0 = 0; k0 < K; k0 += 4){
      float4 xv = *(const float4*)(xrow + k0);
      #pragma unroll
      for (int kk = 0; kk < 4; ++kk){
        float xs = kk==0 ? xv.x : kk==1 ? xv.y : kk==2 ? xv.z : xv.w;
        int k = k0 + kk;
        #pragma unroll
        for (int c = 0; c < 32; c += 4){
          float4 wl4 = *(const float4*)(wl + k*D_HID + c);
          float4 wr4 = *(const float4*)(wr + k*D_HID + c);
          accl[c+0] = fmaf(xs, wl4.x, accl[c+0]);
          accl[c+1] = fmaf(xs, wl4.y, accl[c+1]);
          accl[c+2] = fmaf(xs, wl4.z, accl[c+2]);
          accl[c+3] = fmaf(xs, wl4.w, accl[c+3]);
          accr[c+0] = fmaf(xs, wr4.x, accr[c+0]);
          accr[c+1] = fmaf(xs, wr4.y, accr[c+1]);
          accr[c+2] = fmaf(xs, wr4.z, accr[c+2]);
          accr[c+3] = fmaf(xs, wr4.w, accr[c+3]);
        }
      }
    }
  } else {
    for (int k = 0; k < K; ++k){
      float xs = ldf(X, 0, (long long)n*K + k);
      #pragma unroll
      for (int c = 0; c < 32; ++c){
        accl[c] = fmaf(xs, ldf(Wl, 0, k*D_HID + c), accl[c]);
        accr[c] = fmaf(xs, ldf(Wr, 0, k*D_HID + c), accr[c]);
      }
    }
  }

  float* lo = xl + (size_t)n * D_HID;
  float* ro = xr + (size_t)n * D_HID;
  #pragma unroll
  for (int c = 0; c < 32; c += 4){
    *(float4*)(lo + c) = make_float4(accl[c], accl[c+1], accl[c+2], accl[c+3]);
    *(float4*)(ro + c) = make_float4(accr[c], accr[c+1], accr[c+2], accr[c+3]);
  }
}

// ---------------- bucket count (LDS histogram, verified r8) ----------------
__global__ void bucket_count(const int* __restrict__ ei, const int* __restrict__ flags,
                             int* __restrict__ gcnt, int E_, int B_){
  __shared__ int hist[MAXB];
  for (int i = threadIdx.x; i < B_; i += 256) hist[i] = 0;
  __syncthreads();
  int chunk = (E_ + gridDim.x - 1) / gridDim.x;
  int s = blockIdx.x * chunk;
  int e = s + chunk; if (e > E_) e = E_;
  int is64 = flags[0];
  for (int i = s + (int)threadIdx.x; i < e; i += 256){
    int dst = is64 ? ei[2*E_ + 2*i] : ei[E_ + i];
    atomicAdd(&hist[dst >> BSH], 1);
  }
  __syncthreads();
  for (int i = threadIdx.x; i < B_; i += 256)
    if (hist[i]) (void)atomAddI(&gcnt[i], hist[i]);
}

// ---------------- exclusive scan over bucket counts (verified r8) ----------------
__global__ void scan_buckets(const int* __restrict__ gcnt, int* __restrict__ offsets,
                             int* __restrict__ cursor, int B_){
  __shared__ int sd[1024];
  int t = threadIdx.x;
  int v = (t < B_) ? gcnt[t] : 0;
  sd[t] = v;
  __syncthreads();
  for (int off = 1; off < 1024; off <<= 1){
    int tmp = (t >= off) ? sd[t-off] : 0;
    __syncthreads();
    sd[t] += tmp;
    __syncthreads();
  }
  if (t < B_){
    int excl = sd[t] - v;
    offsets[t] = excl;
    cursor[t]  = excl;
    if (t == B_-1) offsets[B_] = sd[t];
  }
}

// ---------------- bucket scatter with per-block range reservation (verified r8) ---
__global__ void bucket_scatter(const int* __restrict__ ei, const int* __restrict__ flags,
                               int* __restrict__ cursor, unsigned* __restrict__ seg,
                               int E_, int B_){
  __shared__ int hist[MAXB];
  __shared__ int bbase[MAXB];
  for (int i = threadIdx.x; i < B_; i += 256) hist[i] = 0;
  __syncthreads();
  int chunk = (E_ + gridDim.x - 1) / gridDim.x;
  int s = blockIdx.x * chunk;
  int e = s + chunk; if (e > E_) e = E_;
  int is64 = flags[0];
  for (int i = s + (int)threadIdx.x; i < e; i += 256){
    int dst = is64 ? ei[2*E_ + 2*i] : ei[E_ + i];
    atomicAdd(&hist[dst >> BSH], 1);
  }
  __syncthreads();
  for (int i = threadIdx.x; i < B_; i += 256){
    int c = hist[i];
    bbase[i] = c ? atomAddI(&cursor[i], c) : 0;
  }
  __syncthreads();
  for (int i = threadIdx.x; i < B_; i += 256) hist[i] = 0;  // reuse as local offset
  __syncthreads();
  for (int i = s + (int)threadIdx.x; i < e; i += 256){
    int src, dst;
    edge_nodes(ei, E_, is64, i, src, dst);
    int b = dst >> BSH;
    int pos = bbase[b] + atomicAdd(&hist[b], 1);
    seg[pos] = ((unsigned)src << BSH) | (unsigned)(dst & (BSZ-1));
  }
}

// ---------------- bucket finalize: exact per-dst CSR from bucket segments --------
// One block per bucket: LDS histogram of 128 local dsts over the contiguous seg
// slice, LDS scan -> row[] (global offsets), then dense re-scatter into csr_src.
// All global traffic is contiguous per bucket (L2-local).
__global__ void bucket_finalize(const unsigned* __restrict__ seg,
                                const int* __restrict__ offsets,
                                int* __restrict__ row, int* __restrict__ csr_src,
                                int N_, int B_){
  __shared__ int hist[BSZ];
  __shared__ int sc[BSZ];
  __shared__ int loff[BSZ];
  int b = blockIdx.x;
  int t = threadIdx.x;
  int base = offsets[b], cnt = offsets[b+1] - base;
  if (t < BSZ) hist[t] = 0;
  __syncthreads();
  for (int i = t; i < cnt; i += 256)
    atomicAdd(&hist[seg[base+i] & (BSZ-1)], 1);
  __syncthreads();
  if (t < BSZ) sc[t] = hist[t];
  __syncthreads();
  for (int off = 1; off < BSZ; off <<= 1){
    int tmp = (t < BSZ && t >= off) ? sc[t-off] : 0;
    __syncthreads();
    if (t < BSZ) sc[t] += tmp;
    __syncthreads();
  }
  if (t < BSZ){
    int excl = sc[t] - hist[t];
    loff[t] = excl;
    int node = b*BSZ + t;
    if (node <= N_) row[node] = base + excl;   // covers row[N_] when N_ inside bucket
  }
  if (b == B_-1 && t == 0) row[N_] = offsets[B_];
  __syncthreads();
  for (int i = t; i < cnt; i += 256){
    unsigned en = seg[base+i];
    int dl = en & (BSZ-1);
    int pos = atomicAdd(&loff[dl], 1);
    csr_src[base + pos] = (int)(en >> BSH);
  }
}

// ---------------- fused per-dst gather: softmax + weighted sum + bias ------------
// Wave per dst (r7-verified structure), no LDS. Each half-wave pipelines 4 edges:
// 4 index loads then 4 xl gathers issued before any reduce (8 outstanding
// gathers/wave). All guards half-wave-uniform; no cross-half data movement until
// the final combine.
__global__ void gat_gather(const int* __restrict__ row, const int* __restrict__ csr_src,
                           const float* __restrict__ xl, const float* __restrict__ xr,
                           const void* __restrict__ att, const void* __restrict__ bias,
                           const int* __restrict__ flags,
                           float* __restrict__ outp, int N_, int do_relu)
{
  int n = blockIdx.x * (blockDim.x >> 6) + (threadIdx.x >> 6);
  if (n >= N_) return;
  int lane = threadIdx.x & 63;
  int half = lane >> 5, k = lane & 31;
  int f32 = flags[1];
  float attk = ldf(att, f32, k);
  float xrk = xr[(size_t)n*D_HID + k];
  int rs = row[n], re = row[n+1];
  float acc = 0.f, ssum = 0.f;
  for (int i0 = rs + half; i0 < re; i0 += 8){   // this half's edges: i0+{0,2,4,6}
    float xlv[4];
    int valid[4];
    #pragma unroll
    for (int u = 0; u < 4; ++u){
      int i = i0 + 2*u;
      valid[u] = (i < re);
      int ic = valid[u] ? i : (re - 1);          // clamped: always-legal address
      int src = csr_src[ic];
      xlv[u] = xl[(size_t)src*D_HID + k];
    }
    #pragma unroll
    for (int u = 0; u < 4; ++u){
      if (valid[u]){                             // uniform within the half-wave
        float h = xlv[u] + xrk;
        h = h > 0.f ? h : NEG*h;
        float p = h * attk;
        p += __shfl_xor(p, 16, 32);
        p += __shfl_xor(p,  8, 32);
        p += __shfl_xor(p,  4, 32);
        p += __shfl_xor(p,  2, 32);
        p += __shfl_xor(p,  1, 32);
        p = fminf(p, 60.f);                      // safety clamp; real logits |.| <~ 15
        float ev = __expf(p);
        ssum += ev;
        acc = fmaf(ev, xlv[u], acc);
      }
    }
  }
  // combine the two half-wave partial sums (lane^32 has same k)
  acc  += __shfl_xor(acc, 32, 64);
  ssum += __shfl_xor(ssum, 32, 64);
  if (half == 0){
    float v = acc / (ssum + 1e-16f) + ldf(bias, f32, k);
    if (do_relu) v = v > 0.f ? v : 0.f;
    outp[(size_t)n*D_HID + k] = v;
  }
}

extern "C" void kernel_launch(void* const* d_in, const int* in_sizes, int n_in,
                              void* d_out, int out_size, void* d_ws, size_t ws_size,
                              hipStream_t stream)
{
  const void* x   = d_in[0];
  const int*  ei  = (const int*)d_in[1];
  const void* W1l = d_in[2];
  const void* W1r = d_in[3];
  const void* att1= d_in[4];
  const void* b1  = d_in[5];
  const void* W2l = d_in[6];
  const void* W2r = d_in[7];
  const void* att2= d_in[8];
  const void* b2  = d_in[9];
  float* out = (float*)d_out;

  int N_ = in_sizes[0] / D_IN;
  int E_ = in_sizes[1] / 2;
  int B_ = (N_ + BSZ - 1) / BSZ;

  char* ws = (char*)d_ws;
  size_t off = 0;
  auto carve = [&](size_t bytes) -> char* {
    char* p = ws + off;
    off += (bytes + 255) & ~(size_t)255;
    return p;
  };
  float*    xl      = (float*)   carve((size_t)N_ * D_HID * 4);
  float*    xr      = (float*)   carve((size_t)N_ * D_HID * 4);
  float*    h       = (float*)   carve((size_t)N_ * D_HID * 4);
  unsigned* seg     = (unsigned*)carve((size_t)E_ * 4);
  int*      csr_src = (int*)     carve((size_t)E_ * 4);
  int*      row     = (int*)     carve((size_t)(N_ + 1) * 4);
  int*      offsets = (int*)     carve((size_t)(MAXB + 1) * 4);
  int*      gcnt    = (int*)     carve((size_t)MAXB * 4);
  int*      cursor  = (int*)     carve((size_t)MAXB * 4);
  int*      flags   = (int*)     carve(256);

  const int tpb = 256;
  int gN = (N_ + tpb - 1) / tpb;
  int gW = (N_ + 3) / 4;                    // wave-per-dst grid (4 waves/block)

  detect_flags<<<1, 256, 0, stream>>>(ei, (const u16*)x, flags);

  // ---- CSR build: bucket scatter + per-bucket finalize (shared by both layers) ----
  hipMemsetAsync(gcnt, 0, (size_t)MAXB * 4, stream);
  bucket_count<<<256, tpb, 0, stream>>>(ei, flags, gcnt, E_, B_);
  scan_buckets<<<1, 1024, 0, stream>>>(gcnt, offsets, cursor, B_);
  bucket_scatter<<<256, tpb, 0, stream>>>(ei, flags, cursor, seg, E_, B_);
  bucket_finalize<<<B_, tpb, 0, stream>>>(seg, offsets, row, csr_src, N_, B_);

  // ---- layer 1 ----
  node_gemm<D_IN><<<gN, tpb, 0, stream>>>(x, W1l, W1r, flags, 0, xl, xr, N_);
  gat_gather<<<gW, tpb, 0, stream>>>(row, csr_src, xl, xr, att1, b1, flags, h, N_, 1);

  // ---- layer 2 ----
  node_gemm<D_HID><<<gN, tpb, 0, stream>>>(h, W2l, W2r, flags, 1, xl, xr, N_);
  gat_gather<<<gW, tpb, 0, stream>>>(row, csr_src, xl, xr, att2, b2, flags, out, N_, 0);
}